// Round 8
// baseline (203.010 us; speedup 1.0000x reference)
//
#include <hip/hip_runtime.h>

typedef __bf16 bf16_t;
typedef __bf16 bf16x8 __attribute__((ext_vector_type(8)));
typedef __bf16 bf16x4 __attribute__((ext_vector_type(4)));
typedef float f32x4 __attribute__((ext_vector_type(4)));

#define BN 256
#define BK 64

// ws layout (bytes):
//   0        W1b   (512*512 bf16)  = 524288
//   524288   W2t   (512*512 bf16)  = 524288
//   1048576  W4t   (512*1536 bf16) = 1572864
//   2621440  Wct   (512*512 bf16)  = 524288
//   3145728  bc    (512 f32)       = 2048
//   3147776  u     (512 f32)       = 2048
//   3149824  c3    (3*24576 f32)   = 294912
//   3444736  G2b   (24576*512 bf16)= 25165824
// Gb (bf16 g) lives in d_out chunk0 (dead before final GEMM overwrites with xbo).

__device__ __forceinline__ void g2l16(const void* g, void* l) {
    __builtin_amdgcn_global_load_lds((__attribute__((address_space(1))) void*)(g),
                                     (__attribute__((address_space(3))) void*)(l),
                                     16, 0, 0);
}

#define SB()  __builtin_amdgcn_sched_barrier(0)
#define BAR() __builtin_amdgcn_s_barrier()

// 4-phase double-buffered 8-wave GEMM (R5 config: tile (MF*32)x256, BK=64,
// 512 thr, waves 2x4, LDS swizzle byte^=((row&7)<<4) both-sides, 0 conflicts).
// ASRC = A-operand source:
//   0: bf16 matrix, g2l16-staged (source-inverse-swizzled, linear LDS dest)
//   1: f32 matrix (x) — reg-staged: global f32x4 -> cvt bf16 -> swizzled ds_write
//   2: bf16 g^2 matrix scaled by c_l[row] (l = kt>>3) — reg-staged
// mode: 0 = store bf16; 1 = store f32 silu; 2 = dual store bf16 g and bf16 g^2
template<int MF, int ASRC>
__global__ __launch_bounds__(512)
void gemm_bt_kernel(const void* __restrict__ Asrc, const bf16_t* __restrict__ Bt,
                    const float* __restrict__ bias, const float* __restrict__ cvec,
                    void* __restrict__ Cout, void* __restrict__ Cout2,
                    int N, int K, int mode, int CM)
{
    constexpr int MF2    = MF / 2;
    constexpr int ABYTES = MF * 4096;          // per A buffer: MF*32 rows x 128B
    constexpr int RA     = MF / 2;             // g2l16 A rounds (64 rows / 8KB each)

    __shared__ __align__(16) bf16_t lA[2][MF * 2048];
    __shared__ __align__(16) bf16_t lB[2][16384];

    const int tid  = threadIdx.x;
    const int lane = tid & 63;
    const int wave = tid >> 6;       // 0..7
    const int wr   = wave >> 2;      // 0..1
    const int wc   = wave & 3;       // 0..3
    const int l15  = lane & 15;
    const int lh   = lane >> 4;      // 0..3

    const int bm = blockIdx.x;
    const int bn = blockIdx.y;

    const int q0 = tid * 16;                   // linear byte in one 8KB round
    char* baseA = (char*)&lA[0][0];
    char* baseB = (char*)&lB[0][0];

    // ---- B staging: g2l16, 4 rounds x 8KB (64 rows x 128B) ----
    const size_t strbB = (size_t)K * 2;
    const size_t rowOffB = (size_t)(q0 >> 7) * strbB + ((q0 ^ (((q0 >> 7) & 7) << 4)) & 127);
    const char* gB = (const char*)Bt + (size_t)bn * BN * strbB + rowOffB;
    auto stageB = [&](int t, int buf, int r) {
        g2l16(gB + (size_t)t * 128 + (size_t)(r * 64) * strbB,
              baseB + buf * 32768 + r * 8192 + q0);
    };

    // ---- A staging, three variants ----
    // ASRC 0
    const size_t strbA = (size_t)K * 2;
    const size_t rowOffA = (size_t)(q0 >> 7) * strbA + ((q0 ^ (((q0 >> 7) & 7) << 4)) & 127);
    const char* gA0 = (const char*)Asrc + (size_t)bm * (MF * 32) * strbA + rowOffA;
    auto stageA0 = [&](int t, int buf, int r) {
        g2l16(gA0 + (size_t)t * 128 + (size_t)(r * 64) * strbA,
              baseA + buf * ABYTES + r * 8192 + q0);
    };
    // ASRC 1: f32 source, 6 rounds x 32 rows (MF=6). lrX in [0,32), cbX in [0,256)
    const int lrX = q0 >> 8, cbX = q0 & 255;
    const size_t strbX = (size_t)K * 4;
    const char* gA1 = (const char*)Asrc + ((size_t)bm * (MF * 32) + lrX) * strbX + cbX;
    const int wbyteX = ((lrX * 128) + (cbX >> 1)) ^ ((lrX & 7) << 4);  // per-round +32row = +4096B
    // ASRC 2: bf16 g^2 source (row len 512), 3 rounds x 64 rows. lr2 in [0,64)
    const int lr2 = q0 >> 7, cb2 = q0 & 127;
    const char* gA2 = (const char*)Asrc + ((size_t)bm * (MF * 32) + lr2) * 1024 + cb2;
    const int wbyte2 = ((lr2 * 128) + cb2) ^ ((lr2 & 7) << 4);         // per-round +64row = +8192B
    float cpre[3][3];   // [l][round]
    if (ASRC == 2) {
#pragma unroll
        for (int l = 0; l < 3; ++l)
#pragma unroll
            for (int r = 0; r < 3; ++r)
                cpre[l][r] = cvec[(size_t)l * CM + bm * (MF * 32) + r * 64 + lr2];
    }

    // ---- swizzled read addresses ----
    const int swzr = (l15 & 7) << 4;
    const int xk0  = (lh * 16) ^ swzr;
    const int xk1  = (64 + lh * 16) ^ swzr;
    const int aOff = wr * (MF2 * 2) * 2048 + l15 * 128;
    const int bOff = wc * 8192 + l15 * 128;

    f32x4 acc[2][2][MF2][2] = {};

#define LOADA(AF, BUF_, MH_) do{ \
    const char* _p = baseA + (BUF_)*ABYTES + aOff + (MH_)*(MF2*2048); \
    _Pragma("unroll") for (int m = 0; m < MF2; ++m) { \
        AF[m][0] = *(const bf16x8*)(_p + m*2048 + xk0); \
        AF[m][1] = *(const bf16x8*)(_p + m*2048 + xk1); } }while(0)
#define LOADB(BF, BUF_, NH_) do{ \
    const char* _p = baseB + (BUF_)*32768 + bOff + (NH_)*4096; \
    _Pragma("unroll") for (int n = 0; n < 2; ++n) { \
        BF[n][0] = *(const bf16x8*)(_p + n*2048 + xk0); \
        BF[n][1] = *(const bf16x8*)(_p + n*2048 + xk1); } }while(0)
#define MMAQ(MH_, NH_, AF, BF) do{ \
    __builtin_amdgcn_s_setprio(1); \
    _Pragma("unroll") for (int m = 0; m < MF2; ++m) \
    _Pragma("unroll") for (int n = 0; n < 2; ++n) \
    _Pragma("unroll") for (int kk = 0; kk < 2; ++kk) \
        acc[MH_][NH_][m][n] = __builtin_amdgcn_mfma_f32_16x16x32_bf16( \
            AF[m][kk], BF[n][kk], acc[MH_][NH_][m][n], 0, 0, 0); \
    __builtin_amdgcn_s_setprio(0); }while(0)

    const int T = K / BK;

    float4  af[6];        // ASRC 1 in-flight A loads
    bf16x8  ag[3];        // ASRC 2 in-flight A loads

    auto issueA = [&](int t) {
        if (ASRC == 1) {
#pragma unroll
            for (int r = 0; r < 6; ++r)
                af[r] = *(const float4*)(gA1 + (size_t)t * 256 + (size_t)(r * 32) * strbX);
        } else if (ASRC == 2) {
#pragma unroll
            for (int r = 0; r < 3; ++r)
                ag[r] = *(const bf16x8*)(gA2 + (size_t)(t & 7) * 128 + r * 65536);
        }
    };
    auto writeA = [&](int t, int buf) {
        if (ASRC == 1) {
#pragma unroll
            for (int r = 0; r < 6; ++r) {
                bf16x4 o;
                o[0] = (bf16_t)af[r].x; o[1] = (bf16_t)af[r].y;
                o[2] = (bf16_t)af[r].z; o[3] = (bf16_t)af[r].w;
                *(bf16x4*)(baseA + buf * ABYTES + r * 4096 + wbyteX) = o;
            }
        } else if (ASRC == 2) {
            const int l = t >> 3;
            const float c0 = cpre[0][0], c1 = cpre[1][0], c2 = cpre[2][0];
#pragma unroll
            for (int r = 0; r < 3; ++r) {
                const float cv = (l == 0) ? cpre[0][r] : (l == 1) ? cpre[1][r] : cpre[2][r];
                bf16x8 o;
#pragma unroll
                for (int j = 0; j < 8; ++j) o[j] = (bf16_t)(cv * (float)ag[r][j]);
                *(bf16x8*)(baseA + buf * ABYTES + r * 8192 + wbyte2) = o;
            }
            (void)c0; (void)c1; (void)c2;
        }
    };

    // ---- prologue: stage tile 0 ----
    if (ASRC == 0) {
#pragma unroll
        for (int r = 0; r < RA; ++r) stageA0(0, 0, r);
    } else {
        issueA(0); writeA(0, 0);
    }
#pragma unroll
    for (int r = 0; r < 4; ++r) stageB(0, 0, r);
    asm volatile("s_waitcnt vmcnt(0) lgkmcnt(0)" ::: "memory");
    BAR();

    for (int t = 0; t < T; ++t) {
        const int buf = t & 1, nbuf = buf ^ 1;
        const bool pf = (t + 1 < T);
        bf16x8 a0[MF2][2], a1[MF2][2], b0[2][2], b1[2][2];

        // phase 1: quadrant (0,0); A staging for t+1 (g2l16 or issue loads)
        LOADA(a0, buf, 0); LOADB(b0, buf, 0);
        if (pf) {
            if (ASRC == 0) {
#pragma unroll
                for (int r = 0; r < RA; ++r) stageA0(t + 1, nbuf, r);
            } else issueA(t + 1);
        }
        SB(); BAR();
        MMAQ(0, 0, a0, b0);
        SB(); BAR();

        // phase 2: quadrant (0,1); B staging for t+1
        LOADB(b1, buf, 1);
        if (pf) {
#pragma unroll
            for (int r = 0; r < 4; ++r) stageB(t + 1, nbuf, r);
        }
        SB(); BAR();
        MMAQ(0, 1, a0, b1);
        SB(); BAR();

        // phase 3: quadrant (1,0); reg-staged A convert+write -> nbuf
        LOADA(a1, buf, 1);
        if (pf && ASRC != 0) writeA(t + 1, nbuf);
        SB(); BAR();
        MMAQ(1, 0, a1, b0);
        SB(); BAR();

        // phase 4: quadrant (1,1); boundary drain (loads >= 2 phases old)
        SB(); BAR();
        MMAQ(1, 1, a1, b1);
        SB();
        asm volatile("s_waitcnt vmcnt(0) lgkmcnt(0)" ::: "memory");
        BAR();
    }

    // C/D frag layout: col = lane&15, row = (lane>>4)*4 + j
    const int gr0 = bm * (MF * 32) + wr * (MF2 * 32) + lh * 4;
    const int gc0 = bn * BN + wc * 64 + l15;
    if (mode == 0) {
        bf16_t* C = (bf16_t*)Cout;
#pragma unroll
        for (int mh = 0; mh < 2; ++mh)
#pragma unroll
        for (int nh = 0; nh < 2; ++nh)
#pragma unroll
        for (int m = 0; m < MF2; ++m)
#pragma unroll
        for (int n = 0; n < 2; ++n) {
            const int c = gc0 + nh * 32 + n * 16;
            const float bv = bias ? bias[c] : 0.f;
#pragma unroll
            for (int j = 0; j < 4; ++j) {
                const int r = gr0 + (mh * MF2 + m) * 16 + j;
                C[(size_t)r * N + c] = (bf16_t)(acc[mh][nh][m][n][j] + bv);
            }
        }
    } else if (mode == 2) {
        bf16_t* C  = (bf16_t*)Cout;
        bf16_t* C2 = (bf16_t*)Cout2;
#pragma unroll
        for (int mh = 0; mh < 2; ++mh)
#pragma unroll
        for (int nh = 0; nh < 2; ++nh)
#pragma unroll
        for (int m = 0; m < MF2; ++m)
#pragma unroll
        for (int n = 0; n < 2; ++n) {
            const int c = gc0 + nh * 32 + n * 16;
            const float bv = bias ? bias[c] : 0.f;
#pragma unroll
            for (int j = 0; j < 4; ++j) {
                const int r = gr0 + (mh * MF2 + m) * 16 + j;
                const float v = acc[mh][nh][m][n][j] + bv;
                C [(size_t)r * N + c] = (bf16_t)v;
                C2[(size_t)r * N + c] = (bf16_t)(v * v);
            }
        }
    } else {
        float* C = (float*)Cout;
#pragma unroll
        for (int mh = 0; mh < 2; ++mh)
#pragma unroll
        for (int nh = 0; nh < 2; ++nh)
#pragma unroll
        for (int m = 0; m < MF2; ++m)
#pragma unroll
        for (int n = 0; n < 2; ++n) {
            const int c = gc0 + nh * 32 + n * 16;
            const float bv = bias[c];
#pragma unroll
            for (int j = 0; j < 4; ++j) {
                const int r = gr0 + (mh * MF2 + m) * 16 + j;
                float v = acc[mh][nh][m][n][j] + bv;
                C[(size_t)r * N + c] = v / (1.f + __expf(-v));
            }
        }
    }
#undef LOADA
#undef LOADB
#undef MMAQ
}

__global__ void cast8_kernel(const float* __restrict__ in, bf16_t* __restrict__ out, int n8) {
    const int i = blockIdx.x * blockDim.x + threadIdx.x;
    if (i >= n8) return;
    const float4* p = (const float4*)in + (size_t)i * 2;
    float4 a = p[0], b = p[1];
    bf16x8 v;
    v[0] = (bf16_t)a.x; v[1] = (bf16_t)a.y; v[2] = (bf16_t)a.z; v[3] = (bf16_t)a.w;
    v[4] = (bf16_t)b.x; v[5] = (bf16_t)b.y; v[6] = (bf16_t)b.z; v[7] = (bf16_t)b.w;
    *(bf16x8*)(out + (size_t)i * 8) = v;
}

__global__ void transpose_cast_kernel(const float* __restrict__ in, bf16_t* __restrict__ out,
                                      int R, int C) {
    const int idx = blockIdx.x * blockDim.x + threadIdx.x;
    if (idx >= R * C) return;
    const int c = idx / R;
    const int r = idx - c * R;
    out[idx] = (bf16_t)in[(size_t)r * C + c];
}

// u[t] = sum_i v[i] * W[i][t]
__global__ void vecmat_kernel(const float* __restrict__ v, const float* __restrict__ W,
                              float* __restrict__ out) {
    const int t = blockIdx.x * blockDim.x + threadIdx.x;
    if (t >= 512) return;
    float s = 0.f;
    for (int i = 0; i < 512; ++i) s += v[i] * W[i * 512 + t];
    out[t] = s;
}

// per node: s = g.W3 ; chi_bo = chi*s ; c3[l][n] = sum_{m in seg l} chi^2
__global__ __launch_bounds__(256)
void stats_kernel(const bf16_t* __restrict__ G, const float* __restrict__ chi,
                  const float* __restrict__ W3, float* __restrict__ chbo,
                  float* __restrict__ c3)
{
    const int node = blockIdx.x * 4 + (threadIdx.x >> 6);
    const int lane = threadIdx.x & 63;

    const bf16x8 gv = *(const bf16x8*)(G + (size_t)node * 512 + lane * 8);
    float s = 0.f;
    const float* w = W3 + lane * 8;
#pragma unroll
    for (int j = 0; j < 8; ++j) s += (float)gv[j] * w[j];
#pragma unroll
    for (int off = 32; off > 0; off >>= 1) s += __shfl_xor(s, off, 64);

    const float* ch = chi + (size_t)node * 15;
    float c0 = 0.f, c1 = 0.f, c2 = 0.f;
#pragma unroll
    for (int m = 0; m < 3; ++m)  c0 += ch[m] * ch[m];
#pragma unroll
    for (int m = 3; m < 8; ++m)  c1 += ch[m] * ch[m];
#pragma unroll
    for (int m = 8; m < 15; ++m) c2 += ch[m] * ch[m];

    if (lane < 15) chbo[(size_t)node * 15 + lane] = ch[lane] * s;
    if (lane == 0) {
        c3[node]             = c0;
        c3[24576 + node]     = c1;
        c3[2 * 24576 + node] = c2;
    }
}

extern "C" void kernel_launch(void* const* d_in, const int* in_sizes, int n_in,
                              void* d_out, int out_size, void* d_ws, size_t ws_size,
                              hipStream_t stream)
{
    const float* x   = (const float*)d_in[0];
    const float* chi = (const float*)d_in[1];
    // d_in[2] = z_one_hot : unused by the reference computation
    const float* W1  = (const float*)d_in[3];
    const float* b1  = (const float*)d_in[4];
    const float* W2  = (const float*)d_in[5];
    const float* W3  = (const float*)d_in[6];
    const float* W4  = (const float*)d_in[7];
    const float* b4  = (const float*)d_in[8];

    char* ws = (char*)d_ws;
    bf16_t* W1b = (bf16_t*)(ws + 0);
    bf16_t* W2t = (bf16_t*)(ws + 524288);
    bf16_t* W4t = (bf16_t*)(ws + 1048576);
    bf16_t* Wct = (bf16_t*)(ws + 2621440);
    float*  bc  = (float*) (ws + 3145728);
    float*  u   = (float*) (ws + 3147776);
    float*  c3  = (float*) (ws + 3149824);
    bf16_t* G2b = (bf16_t*)(ws + 3444736);

    float*  xbo  = (float*)d_out;                                // 24576*512 f32
    float*  chbo = (float*)d_out + (size_t)24576 * 512;          // 24576*15 f32
    bf16_t* Gb   = (bf16_t*)d_out;   // bf16 scratch in chunk0 (dead before final GEMM)

    // prep: weight casts / transposes / fused bias  bc = (b1 @ W1) @ W2
    cast8_kernel<<<128, 256, 0, stream>>>(W1, W1b, 32768);
    transpose_cast_kernel<<<1024, 256, 0, stream>>>(W2, W2t, 512, 512);
    transpose_cast_kernel<<<3072, 256, 0, stream>>>(W4, W4t, 1536, 512);
    vecmat_kernel<<<2, 256, 0, stream>>>(b1, W1, u);
    vecmat_kernel<<<2, 256, 0, stream>>>(u, W2, bc);

    // Wct = (W1@W2)^T = W2^T @ W1^T
    gemm_bt_kernel<8, 0><<<dim3(2, 2), 512, 0, stream>>>(
        W2t, W1b, nullptr, nullptr, Wct, nullptr, 512, 512, 0, 0);

    // G = x @ (W1@W2) + bc  (A = f32 x, reg-staged); writes Gb and G2b = bf16(g^2)
    gemm_bt_kernel<6, 1><<<dim3(128, 2), 512, 0, stream>>>(
        x, Wct, bc, nullptr, Gb, G2b, 512, 512, 2, 0);

    // s, chi_bo, c3
    stats_kernel<<<6144, 256, 0, stream>>>(Gb, chi, W3, chbo, c3);

    // x_bo = silu(A3 @ W4 + b4), A3-tile built on the fly: c_l[row] * G2[row,k]
    gemm_bt_kernel<6, 2><<<dim3(128, 2), 512, 0, stream>>>(
        G2b, W4t, b4, c3, xbo, nullptr, 512, 1536, 1, 24576);
}

// Round 9
// 180.016 us; speedup vs baseline: 1.1277x; 1.1277x over previous
//
#include <hip/hip_runtime.h>

typedef __bf16 bf16_t;
typedef __bf16 bf16x8 __attribute__((ext_vector_type(8)));
typedef float f32x4 __attribute__((ext_vector_type(4)));

#define BN 256
#define BK 64

// ws layout (bytes):
//   0        W1b   (512*512 bf16)  = 524288
//   524288   W2t   (512*512 bf16)  = 524288
//   1048576  W4t   (512*1536 bf16) = 1572864
//   2621440  Wct   (512*512 bf16)  = 524288
//   3145728  bc    (512 f32)       = 2048
//   3147776  u     (512 f32)       = 2048
//   3149824  Xb / A3 (overlapped; max = 24576*1536*2 = 75497472)

__device__ __forceinline__ void g2l16(const void* g, void* l) {
    __builtin_amdgcn_global_load_lds((__attribute__((address_space(1))) void*)(g),
                                     (__attribute__((address_space(3))) void*)(l),
                                     16, 0, 0);
}

#define SB()  __builtin_amdgcn_sched_barrier(0)
#define BAR() __builtin_amdgcn_s_barrier()

// Double-buffered 8-wave GEMM, tile (MF*32)x256, BK=64, ONE barrier per K-tile.
// Hazard model (why 1 barrier suffices):
//  - tile t reads LDS buf, writes LDS nbuf via g2l16 -> disjoint, no intra-tile sync.
//  - each wave's ds_reads complete before its own MFMAs (compiler lgkmcnt), so
//    barrier arrival implies reads done -> next tile's writes to buf are safe.
//  - RAW on buf: per-wave vmcnt(0) at tile start waits only on loads issued a
//    full tile earlier (>=3000 cyc old -> landed; wait is ~free), then barrier
//    publishes all waves' loads.  [T4: never block on young loads]
// LDS swizzle byte^=((row&7)<<4), both-sides involution -> 0 bank conflicts (R5-verified).
template<int MF>
__global__ __launch_bounds__(512)
void gemm_bt_kernel(const bf16_t* __restrict__ A, const bf16_t* __restrict__ Bt,
                    const float* __restrict__ bias, void* __restrict__ Cout,
                    int N, int K, int mode)
{
    constexpr int MF2    = MF / 2;
    constexpr int NFA    = MF;                 // A frags per wave (16-row each)
    constexpr int ABYTES = MF * 4096;          // per A buffer: MF*32 rows x 128B
    constexpr int RA     = MF / 2;             // A staging rounds (8KB each)

    __shared__ __align__(16) bf16_t lA[2][MF * 2048];
    __shared__ __align__(16) bf16_t lB[2][16384];

    const int tid  = threadIdx.x;
    const int lane = tid & 63;
    const int wave = tid >> 6;       // 0..7
    const int wr   = wave >> 2;      // 0..1
    const int wc   = wave & 3;       // 0..3
    const int l15  = lane & 15;
    const int lh   = lane >> 4;      // 0..3

    const int bm = blockIdx.x;
    const int bn = blockIdx.y;

    const size_t strb = (size_t)K * 2;

    // ---- staging: one g2l16 round = 8KB (64 rows x 128B), 512 thr x 16B ----
    const int q0 = tid * 16;
    const size_t rowOff = (size_t)(q0 >> 7) * strb + ((q0 ^ (((q0 >> 7) & 7) << 4)) & 127);
    const char* gA = (const char*)A  + (size_t)bm * (MF * 32) * strb + rowOff;
    const char* gB = (const char*)Bt + (size_t)bn * BN * strb + rowOff;
    char* baseA = (char*)&lA[0][0];
    char* baseB = (char*)&lB[0][0];

    auto stageA = [&](int t, int buf, int r) {
        g2l16(gA + (size_t)t * 128 + (size_t)(r * 64) * strb,
              baseA + buf * ABYTES + r * 8192 + q0);
    };
    auto stageB = [&](int t, int buf, int r) {
        g2l16(gB + (size_t)t * 128 + (size_t)(r * 64) * strb,
              baseB + buf * 32768 + r * 8192 + q0);
    };

    // ---- swizzled read addresses ----
    const int swzr = (l15 & 7) << 4;
    const int xk0  = (lh * 16) ^ swzr;
    const int xk1  = (64 + lh * 16) ^ swzr;
    const int aOff = wr * (MF2 * 2) * 2048 + l15 * 128;
    const int bOff = wc * 8192 + l15 * 128;

    f32x4 acc[2][2][MF2][2] = {};

    const int T = K / BK;

    // prologue: stage tile 0
#pragma unroll
    for (int r = 0; r < RA; ++r) stageA(0, 0, r);
#pragma unroll
    for (int r = 0; r < 4; ++r)  stageB(0, 0, r);

    for (int t = 0; t < T; ++t) {
        const int buf = t & 1, nbuf = buf ^ 1;

        // tile-start: own loads (issued a full tile ago) -> landed; publish.
        asm volatile("s_waitcnt vmcnt(0)" ::: "memory");
        BAR();
        SB();

        // issue next tile's staging first (starts HBM early, overlaps compute)
        if (t + 1 < T) {
#pragma unroll
            for (int r = 0; r < RA; ++r) stageA(t + 1, nbuf, r);
#pragma unroll
            for (int r = 0; r < 4; ++r)  stageB(t + 1, nbuf, r);
        }
        SB();

        // read all fragments for this tile
        bf16x8 af[NFA][2], bf[4][2];
        {
            const char* _pa = baseA + buf * ABYTES + aOff;
#pragma unroll
            for (int i = 0; i < NFA; ++i) {
                af[i][0] = *(const bf16x8*)(_pa + i * 2048 + xk0);
                af[i][1] = *(const bf16x8*)(_pa + i * 2048 + xk1);
            }
            const char* _pb = baseB + buf * 32768 + bOff;
#pragma unroll
            for (int j = 0; j < 4; ++j) {
                bf[j][0] = *(const bf16x8*)(_pb + j * 2048 + xk0);
                bf[j][1] = *(const bf16x8*)(_pb + j * 2048 + xk1);
            }
        }

        // 16*MF MFMAs (compiler interleaves with ds_read latency via lgkmcnt)
        __builtin_amdgcn_s_setprio(1);
#pragma unroll
        for (int mh = 0; mh < 2; ++mh)
#pragma unroll
        for (int nh = 0; nh < 2; ++nh)
#pragma unroll
        for (int m = 0; m < MF2; ++m)
#pragma unroll
        for (int n = 0; n < 2; ++n)
#pragma unroll
        for (int kk = 0; kk < 2; ++kk)
            acc[mh][nh][m][n] = __builtin_amdgcn_mfma_f32_16x16x32_bf16(
                af[mh * MF2 + m][kk], bf[nh * 2 + n][kk], acc[mh][nh][m][n], 0, 0, 0);
        __builtin_amdgcn_s_setprio(0);
    }

    // C/D frag layout: col = lane&15, row = (lane>>4)*4 + j
    const int gr0 = bm * (MF * 32) + wr * (MF2 * 32) + lh * 4;
    const int gc0 = bn * BN + wc * 64 + l15;
    if (mode == 0) {
        bf16_t* C = (bf16_t*)Cout;
#pragma unroll
        for (int mh = 0; mh < 2; ++mh)
#pragma unroll
        for (int nh = 0; nh < 2; ++nh)
#pragma unroll
        for (int m = 0; m < MF2; ++m)
#pragma unroll
        for (int n = 0; n < 2; ++n) {
            const int c = gc0 + nh * 32 + n * 16;
            const float bv = bias ? bias[c] : 0.f;
#pragma unroll
            for (int j = 0; j < 4; ++j) {
                const int r = gr0 + (mh * MF2 + m) * 16 + j;
                C[(size_t)r * N + c] = (bf16_t)(acc[mh][nh][m][n][j] + bv);
            }
        }
    } else {
        float* C = (float*)Cout;
#pragma unroll
        for (int mh = 0; mh < 2; ++mh)
#pragma unroll
        for (int nh = 0; nh < 2; ++nh)
#pragma unroll
        for (int m = 0; m < MF2; ++m)
#pragma unroll
        for (int n = 0; n < 2; ++n) {
            const int c = gc0 + nh * 32 + n * 16;
            const float bv = bias[c];
#pragma unroll
            for (int j = 0; j < 4; ++j) {
                const int r = gr0 + (mh * MF2 + m) * 16 + j;
                float v = acc[mh][nh][m][n][j] + bv;
                C[(size_t)r * N + c] = v / (1.f + __expf(-v));
            }
        }
    }
}

__global__ void cast8_kernel(const float* __restrict__ in, bf16_t* __restrict__ out, int n8) {
    const int i = blockIdx.x * blockDim.x + threadIdx.x;
    if (i >= n8) return;
    const float4* p = (const float4*)in + (size_t)i * 2;
    float4 a = p[0], b = p[1];
    bf16x8 v;
    v[0] = (bf16_t)a.x; v[1] = (bf16_t)a.y; v[2] = (bf16_t)a.z; v[3] = (bf16_t)a.w;
    v[4] = (bf16_t)b.x; v[5] = (bf16_t)b.y; v[6] = (bf16_t)b.z; v[7] = (bf16_t)b.w;
    *(bf16x8*)(out + (size_t)i * 8) = v;
}

// fused weight prep: blocks [0,128) cast W1 -> W1b; [128,1152) transpose W2 -> W2t;
// [1152,4224) transpose W4 -> W4t.
__global__ void prep_kernel(const float* __restrict__ W1, bf16_t* __restrict__ W1b,
                            const float* __restrict__ W2, bf16_t* __restrict__ W2t,
                            const float* __restrict__ W4, bf16_t* __restrict__ W4t)
{
    const int b = blockIdx.x;
    if (b < 128) {
        const int i = b * 256 + threadIdx.x;
        const float4* p = (const float4*)W1 + (size_t)i * 2;
        float4 a = p[0], c = p[1];
        bf16x8 v;
        v[0] = (bf16_t)a.x; v[1] = (bf16_t)a.y; v[2] = (bf16_t)a.z; v[3] = (bf16_t)a.w;
        v[4] = (bf16_t)c.x; v[5] = (bf16_t)c.y; v[6] = (bf16_t)c.z; v[7] = (bf16_t)c.w;
        *(bf16x8*)(W1b + (size_t)i * 8) = v;
    } else if (b < 1152) {
        const int idx = (b - 128) * 256 + threadIdx.x;   // out index, out: 512x512
        const int c = idx >> 9, r = idx & 511;
        W2t[idx] = (bf16_t)W2[(size_t)r * 512 + c];
    } else {
        const int idx = (b - 1152) * 256 + threadIdx.x;  // out: 512x1536 (W4t[c][r])
        const int c = idx / 1536, r = idx - c * 1536;    // wait: out[c*R+r], R=1536
        W4t[idx] = (bf16_t)W4[(size_t)r * 512 + c];
    }
}

// u[t] = sum_i v[i] * W[i][t]
__global__ void vecmat_kernel(const float* __restrict__ v, const float* __restrict__ W,
                              float* __restrict__ out) {
    const int t = blockIdx.x * blockDim.x + threadIdx.x;
    if (t >= 512) return;
    float s = 0.f;
    for (int i = 0; i < 512; ++i) s += v[i] * W[i * 512 + t];
    out[t] = s;
}

// per node: s = g.W3 ; chi_bo = chi*s ; A3[n, l*512+f] = c_l * g[f]^2
__global__ __launch_bounds__(256)
void mid_kernel(const bf16_t* __restrict__ G, const float* __restrict__ chi,
                const float* __restrict__ W3, float* __restrict__ chbo,
                bf16_t* __restrict__ A3)
{
    const int node = blockIdx.x * 4 + (threadIdx.x >> 6);
    const int lane = threadIdx.x & 63;

    const bf16x8 gv = *(const bf16x8*)(G + (size_t)node * 512 + lane * 8);
    float g[8];
#pragma unroll
    for (int j = 0; j < 8; ++j) g[j] = (float)gv[j];

    float s = 0.f;
    const float* w = W3 + lane * 8;
#pragma unroll
    for (int j = 0; j < 8; ++j) s += g[j] * w[j];
#pragma unroll
    for (int off = 32; off > 0; off >>= 1) s += __shfl_xor(s, off, 64);

    const float* ch = chi + (size_t)node * 15;
    float c0 = 0.f, c1 = 0.f, c2 = 0.f;
#pragma unroll
    for (int m = 0; m < 3; ++m)  c0 += ch[m] * ch[m];
#pragma unroll
    for (int m = 3; m < 8; ++m)  c1 += ch[m] * ch[m];
#pragma unroll
    for (int m = 8; m < 15; ++m) c2 += ch[m] * ch[m];

    if (lane < 15) chbo[(size_t)node * 15 + lane] = ch[lane] * s;

    const float cl[3] = {c0, c1, c2};
    bf16_t* arow = A3 + (size_t)node * 1536 + lane * 8;
#pragma unroll
    for (int l = 0; l < 3; ++l) {
        bf16x8 o;
#pragma unroll
        for (int j = 0; j < 8; ++j) o[j] = (bf16_t)(cl[l] * g[j] * g[j]);
        *(bf16x8*)(arow + l * 512) = o;
    }
}

extern "C" void kernel_launch(void* const* d_in, const int* in_sizes, int n_in,
                              void* d_out, int out_size, void* d_ws, size_t ws_size,
                              hipStream_t stream)
{
    const float* x   = (const float*)d_in[0];
    const float* chi = (const float*)d_in[1];
    // d_in[2] = z_one_hot : unused by the reference computation
    const float* W1  = (const float*)d_in[3];
    const float* b1  = (const float*)d_in[4];
    const float* W2  = (const float*)d_in[5];
    const float* W3  = (const float*)d_in[6];
    const float* W4  = (const float*)d_in[7];
    const float* b4  = (const float*)d_in[8];

    char* ws = (char*)d_ws;
    bf16_t* W1b = (bf16_t*)(ws + 0);
    bf16_t* W2t = (bf16_t*)(ws + 524288);
    bf16_t* W4t = (bf16_t*)(ws + 1048576);
    bf16_t* Wct = (bf16_t*)(ws + 2621440);
    float*  bc  = (float*) (ws + 3145728);
    float*  u   = (float*) (ws + 3147776);
    bf16_t* Xb  = (bf16_t*)(ws + 3149824);
    bf16_t* A3  = (bf16_t*)(ws + 3149824);   // overlaps Xb (dead by then)

    float*  xbo  = (float*)d_out;                                // 24576*512 f32
    float*  chbo = (float*)d_out + (size_t)24576 * 512;          // 24576*15 f32
    bf16_t* Gb   = (bf16_t*)d_out;   // bf16 scratch in chunk0 (dead before final GEMM)

    // prep
    cast8_kernel<<<6144, 256, 0, stream>>>(x, Xb, 1572864);
    prep_kernel<<<4224, 256, 0, stream>>>(W1, W1b, W2, W2t, W4, W4t);
    vecmat_kernel<<<2, 256, 0, stream>>>(b1, W1, u);
    vecmat_kernel<<<2, 256, 0, stream>>>(u, W2, bc);

    // Wct = (W1@W2)^T = W2^T @ W1^T
    gemm_bt_kernel<8><<<dim3(2, 2), 512, 0, stream>>>(W2t, W1b, nullptr, Wct, 512, 512, 0);

    // G = x @ (W1@W2) + bc -> bf16
    gemm_bt_kernel<6><<<dim3(128, 2), 512, 0, stream>>>(Xb, Wct, bc, Gb, 512, 512, 0);

    // s, chi_bo, A3
    mid_kernel<<<6144, 256, 0, stream>>>(Gb, chi, W3, chbo, A3);

    // x_bo = silu(A3 @ W4 + b4)
    gemm_bt_kernel<6><<<dim3(128, 2), 512, 0, stream>>>(A3, W4t, b4, xbo, 512, 1536, 1);
}

// Round 10
// 173.538 us; speedup vs baseline: 1.1698x; 1.0373x over previous
//
#include <hip/hip_runtime.h>

typedef __bf16 bf16_t;
typedef __bf16 bf16x8 __attribute__((ext_vector_type(8)));
typedef float f32x4 __attribute__((ext_vector_type(4)));

#define BK 64

// ws layout (bytes):
//   0        W1b   (512*512 bf16)  = 524288
//   524288   W2t   (512*512 bf16)  = 524288
//   1048576  W4t   (512*1536 bf16) = 1572864
//   2621440  Wct   (512*512 bf16)  = 524288
//   3145728  bc    (512 f32)       = 2048
//   3147776  u     (512 f32)       = 2048
//   3149824  Xb / A3 (overlapped; max = 24576*1536*2 = 75497472)

__device__ __forceinline__ void g2l16(const void* g, void* l) {
    __builtin_amdgcn_global_load_lds((__attribute__((address_space(1))) void*)(g),
                                     (__attribute__((address_space(3))) void*)(l),
                                     16, 0, 0);
}

#define SB()  __builtin_amdgcn_sched_barrier(0)
#define BAR() __builtin_amdgcn_s_barrier()

// ============ 16-wave GEMM: tile 192x256, BK=64, 1024 threads ============
// Same LDS budget/swizzle/staging as R5/R8 (112 KB, 0 bank conflicts), but
// 16 waves (4x4) instead of 8 -> 4 waves/SIMD: four independent instruction
// streams per SIMD to overlap ds_read latency, g2l16 issue and MFMA.
// Per-wave output 48x64: acc 3x4 f32x4, 24 MFMA/tile.
// One barrier per K-tile (R8 hazard model): vmcnt(0) at tile start waits only
// on loads issued a full tile earlier.
__global__ __launch_bounds__(1024)
void gemm16_kernel(const bf16_t* __restrict__ A, const bf16_t* __restrict__ Bt,
                   const float* __restrict__ bias, void* __restrict__ Cout,
                   int N, int K, int mode)
{
    __shared__ __align__(16) bf16_t lA[2][12288];   // 192 rows x 128B per buf (24 KB)
    __shared__ __align__(16) bf16_t lB[2][16384];   // 256 rows x 128B per buf (32 KB)

    const int tid  = threadIdx.x;
    const int lane = tid & 63;
    const int wave = tid >> 6;       // 0..15
    const int wr   = wave >> 2;      // 0..3 (48-row group)
    const int wc   = wave & 3;       // 0..3 (64-col group)
    const int l15  = lane & 15;
    const int lh   = lane >> 4;      // 0..3

    const int bm = blockIdx.x;
    const int bn = blockIdx.y;

    const size_t strb = (size_t)K * 2;

    // staging: q0 = linear byte within a 16KB round (1024 thr x 16B)
    const int q0 = tid * 16;
    const size_t ro = (size_t)(q0 >> 7) * strb + ((q0 ^ (((q0 >> 7) & 7) << 4)) & 127);
    const char* gA = (const char*)A  + (size_t)bm * 192 * strb + ro;
    const char* gB = (const char*)Bt + (size_t)bn * 256 * strb + ro;
    char* baseA = (char*)&lA[0][0];
    char* baseB = (char*)&lB[0][0];

    // A: 24KB/tile = 16KB round (all threads) + 8KB round (tid<512)
    // B: 32KB/tile = 2 x 16KB rounds
    auto stage = [&](int t, int buf) {
        const size_t kb = (size_t)t * 128;
        g2l16(gA + kb, baseA + buf * 24576 + q0);
        if (tid < 512)
            g2l16(gA + kb + 128 * strb, baseA + buf * 24576 + 16384 + q0);
        g2l16(gB + kb, baseB + buf * 32768 + q0);
        g2l16(gB + kb + 128 * strb, baseB + buf * 32768 + 16384 + q0);
    };

    // swizzled read addresses (row&7 == l15&7 since all row bases are mult of 8)
    const int swzr = (l15 & 7) << 4;
    const int xk0  = (lh * 16) ^ swzr;
    const int xk1  = (64 + lh * 16) ^ swzr;
    const int aOff = (wr * 48 + l15) * 128;
    const int bOff = (wc * 64 + l15) * 128;

    f32x4 acc[3][4] = {};

    const int T = K / BK;
    stage(0, 0);

    for (int t = 0; t < T; ++t) {
        const int buf = t & 1;

        asm volatile("s_waitcnt vmcnt(0)" ::: "memory");  // own tile-t loads: 1 tile old
        BAR();
        SB();

        if (t + 1 < T) stage(t + 1, buf ^ 1);
        SB();

        bf16x8 af[3][2], bf[4][2];
        {
            const char* _pa = baseA + buf * 24576 + aOff;
#pragma unroll
            for (int m = 0; m < 3; ++m) {
                af[m][0] = *(const bf16x8*)(_pa + m * 2048 + xk0);
                af[m][1] = *(const bf16x8*)(_pa + m * 2048 + xk1);
            }
            const char* _pb = baseB + buf * 32768 + bOff;
#pragma unroll
            for (int n = 0; n < 4; ++n) {
                bf[n][0] = *(const bf16x8*)(_pb + n * 2048 + xk0);
                bf[n][1] = *(const bf16x8*)(_pb + n * 2048 + xk1);
            }
        }

        __builtin_amdgcn_s_setprio(1);
#pragma unroll
        for (int m = 0; m < 3; ++m)
#pragma unroll
        for (int n = 0; n < 4; ++n)
#pragma unroll
        for (int kk = 0; kk < 2; ++kk)
            acc[m][n] = __builtin_amdgcn_mfma_f32_16x16x32_bf16(
                af[m][kk], bf[n][kk], acc[m][n], 0, 0, 0);
        __builtin_amdgcn_s_setprio(0);
    }

    // C/D frag layout: col = lane&15, row = (lane>>4)*4 + j
    const int gr0 = bm * 192 + wr * 48 + lh * 4;
    const int gc0 = bn * 256 + wc * 64 + l15;
    if (mode == 0) {
        bf16_t* C = (bf16_t*)Cout;
#pragma unroll
        for (int m = 0; m < 3; ++m)
#pragma unroll
        for (int n = 0; n < 4; ++n) {
            const int c = gc0 + n * 16;
            const float bv = bias ? bias[c] : 0.f;
#pragma unroll
            for (int j = 0; j < 4; ++j) {
                const int r = gr0 + m * 16 + j;
                C[(size_t)r * N + c] = (bf16_t)(acc[m][n][j] + bv);
            }
        }
    } else {
        float* C = (float*)Cout;
#pragma unroll
        for (int m = 0; m < 3; ++m)
#pragma unroll
        for (int n = 0; n < 4; ++n) {
            const int c = gc0 + n * 16;
            const float bv = bias[c];
#pragma unroll
            for (int j = 0; j < 4; ++j) {
                const int r = gr0 + m * 16 + j;
                float v = acc[m][n][j] + bv;
                C[(size_t)r * N + c] = v / (1.f + __expf(-v));
            }
        }
    }
}

// ============ 8-wave GEMM (R8) — used only for the small Wct GEMM ============
template<int MF>
__global__ __launch_bounds__(512)
void gemm_bt_kernel(const bf16_t* __restrict__ A, const bf16_t* __restrict__ Bt,
                    const float* __restrict__ bias, void* __restrict__ Cout,
                    int N, int K, int mode)
{
    constexpr int MF2    = MF / 2;
    constexpr int NFA    = MF;
    constexpr int ABYTES = MF * 4096;
    constexpr int RA     = MF / 2;

    __shared__ __align__(16) bf16_t lA[2][MF * 2048];
    __shared__ __align__(16) bf16_t lB[2][16384];

    const int tid  = threadIdx.x;
    const int lane = tid & 63;
    const int wave = tid >> 6;
    const int wr   = wave >> 2;
    const int wc   = wave & 3;
    const int l15  = lane & 15;
    const int lh   = lane >> 4;

    const int bm = blockIdx.x;
    const int bn = blockIdx.y;

    const size_t strb = (size_t)K * 2;

    const int q0 = tid * 16;
    const size_t rowOff = (size_t)(q0 >> 7) * strb + ((q0 ^ (((q0 >> 7) & 7) << 4)) & 127);
    const char* gA = (const char*)A  + (size_t)bm * (MF * 32) * strb + rowOff;
    const char* gB = (const char*)Bt + (size_t)bn * 256 * strb + rowOff;
    char* baseA = (char*)&lA[0][0];
    char* baseB = (char*)&lB[0][0];

    auto stageA = [&](int t, int buf, int r) {
        g2l16(gA + (size_t)t * 128 + (size_t)(r * 64) * strb,
              baseA + buf * ABYTES + r * 8192 + q0);
    };
    auto stageB = [&](int t, int buf, int r) {
        g2l16(gB + (size_t)t * 128 + (size_t)(r * 64) * strb,
              baseB + buf * 32768 + r * 8192 + q0);
    };

    const int swzr = (l15 & 7) << 4;
    const int xk0  = (lh * 16) ^ swzr;
    const int xk1  = (64 + lh * 16) ^ swzr;
    const int aOff = wr * (MF2 * 2) * 2048 + l15 * 128;
    const int bOff = wc * 8192 + l15 * 128;

    f32x4 acc[2][2][MF2][2] = {};

    const int T = K / BK;

#pragma unroll
    for (int r = 0; r < RA; ++r) stageA(0, 0, r);
#pragma unroll
    for (int r = 0; r < 4; ++r)  stageB(0, 0, r);

    for (int t = 0; t < T; ++t) {
        const int buf = t & 1, nbuf = buf ^ 1;

        asm volatile("s_waitcnt vmcnt(0)" ::: "memory");
        BAR();
        SB();

        if (t + 1 < T) {
#pragma unroll
            for (int r = 0; r < RA; ++r) stageA(t + 1, nbuf, r);
#pragma unroll
            for (int r = 0; r < 4; ++r)  stageB(t + 1, nbuf, r);
        }
        SB();

        bf16x8 af[NFA][2], bf[4][2];
        {
            const char* _pa = baseA + buf * ABYTES + aOff;
#pragma unroll
            for (int i = 0; i < NFA; ++i) {
                af[i][0] = *(const bf16x8*)(_pa + i * 2048 + xk0);
                af[i][1] = *(const bf16x8*)(_pa + i * 2048 + xk1);
            }
            const char* _pb = baseB + buf * 32768 + bOff;
#pragma unroll
            for (int j = 0; j < 4; ++j) {
                bf[j][0] = *(const bf16x8*)(_pb + j * 2048 + xk0);
                bf[j][1] = *(const bf16x8*)(_pb + j * 2048 + xk1);
            }
        }

        __builtin_amdgcn_s_setprio(1);
#pragma unroll
        for (int mh = 0; mh < 2; ++mh)
#pragma unroll
        for (int nh = 0; nh < 2; ++nh)
#pragma unroll
        for (int m = 0; m < MF2; ++m)
#pragma unroll
        for (int n = 0; n < 2; ++n)
#pragma unroll
        for (int kk = 0; kk < 2; ++kk)
            acc[mh][nh][m][n] = __builtin_amdgcn_mfma_f32_16x16x32_bf16(
                af[mh * MF2 + m][kk], bf[nh * 2 + n][kk], acc[mh][nh][m][n], 0, 0, 0);
        __builtin_amdgcn_s_setprio(0);
    }

    const int gr0 = bm * (MF * 32) + wr * (MF2 * 32) + lh * 4;
    const int gc0 = bn * 256 + wc * 64 + l15;
    if (mode == 0) {
        bf16_t* C = (bf16_t*)Cout;
#pragma unroll
        for (int mh = 0; mh < 2; ++mh)
#pragma unroll
        for (int nh = 0; nh < 2; ++nh)
#pragma unroll
        for (int m = 0; m < MF2; ++m)
#pragma unroll
        for (int n = 0; n < 2; ++n) {
            const int c = gc0 + nh * 32 + n * 16;
            const float bv = bias ? bias[c] : 0.f;
#pragma unroll
            for (int j = 0; j < 4; ++j) {
                const int r = gr0 + (mh * MF2 + m) * 16 + j;
                C[(size_t)r * N + c] = (bf16_t)(acc[mh][nh][m][n][j] + bv);
            }
        }
    } else {
        float* C = (float*)Cout;
#pragma unroll
        for (int mh = 0; mh < 2; ++mh)
#pragma unroll
        for (int nh = 0; nh < 2; ++nh)
#pragma unroll
        for (int m = 0; m < MF2; ++m)
#pragma unroll
        for (int n = 0; n < 2; ++n) {
            const int c = gc0 + nh * 32 + n * 16;
            const float bv = bias[c];
#pragma unroll
            for (int j = 0; j < 4; ++j) {
                const int r = gr0 + (mh * MF2 + m) * 16 + j;
                float v = acc[mh][nh][m][n][j] + bv;
                C[(size_t)r * N + c] = v / (1.f + __expf(-v));
            }
        }
    }
}

__global__ void cast8_kernel(const float* __restrict__ in, bf16_t* __restrict__ out, int n8) {
    const int i = blockIdx.x * blockDim.x + threadIdx.x;
    if (i >= n8) return;
    const float4* p = (const float4*)in + (size_t)i * 2;
    float4 a = p[0], b = p[1];
    bf16x8 v;
    v[0] = (bf16_t)a.x; v[1] = (bf16_t)a.y; v[2] = (bf16_t)a.z; v[3] = (bf16_t)a.w;
    v[4] = (bf16_t)b.x; v[5] = (bf16_t)b.y; v[6] = (bf16_t)b.z; v[7] = (bf16_t)b.w;
    *(bf16x8*)(out + (size_t)i * 8) = v;
}

// fused weight prep
__global__ void prep_kernel(const float* __restrict__ W1, bf16_t* __restrict__ W1b,
                            const float* __restrict__ W2, bf16_t* __restrict__ W2t,
                            const float* __restrict__ W4, bf16_t* __restrict__ W4t)
{
    const int b = blockIdx.x;
    if (b < 128) {
        const int i = b * 256 + threadIdx.x;
        const float4* p = (const float4*)W1 + (size_t)i * 2;
        float4 a = p[0], c = p[1];
        bf16x8 v;
        v[0] = (bf16_t)a.x; v[1] = (bf16_t)a.y; v[2] = (bf16_t)a.z; v[3] = (bf16_t)a.w;
        v[4] = (bf16_t)c.x; v[5] = (bf16_t)c.y; v[6] = (bf16_t)c.z; v[7] = (bf16_t)c.w;
        *(bf16x8*)(W1b + (size_t)i * 8) = v;
    } else if (b < 1152) {
        const int idx = (b - 128) * 256 + threadIdx.x;
        const int c = idx >> 9, r = idx & 511;
        W2t[idx] = (bf16_t)W2[(size_t)r * 512 + c];
    } else {
        const int idx = (b - 1152) * 256 + threadIdx.x;
        const int c = idx / 1536, r = idx - c * 1536;
        W4t[idx] = (bf16_t)W4[(size_t)r * 512 + c];
    }
}

// u[t] = sum_i v[i] * W[i][t]
__global__ void vecmat_kernel(const float* __restrict__ v, const float* __restrict__ W,
                              float* __restrict__ out) {
    const int t = blockIdx.x * blockDim.x + threadIdx.x;
    if (t >= 512) return;
    float s = 0.f;
    for (int i = 0; i < 512; ++i) s += v[i] * W[i * 512 + t];
    out[t] = s;
}

// per node: s = g.W3 ; chi_bo = chi*s ; A3[n, l*512+f] = c_l * g[f]^2
__global__ __launch_bounds__(256)
void mid_kernel(const bf16_t* __restrict__ G, const float* __restrict__ chi,
                const float* __restrict__ W3, float* __restrict__ chbo,
                bf16_t* __restrict__ A3)
{
    const int node = blockIdx.x * 4 + (threadIdx.x >> 6);
    const int lane = threadIdx.x & 63;

    const bf16x8 gv = *(const bf16x8*)(G + (size_t)node * 512 + lane * 8);
    float g[8];
#pragma unroll
    for (int j = 0; j < 8; ++j) g[j] = (float)gv[j];

    float s = 0.f;
    const float* w = W3 + lane * 8;
#pragma unroll
    for (int j = 0; j < 8; ++j) s += g[j] * w[j];
#pragma unroll
    for (int off = 32; off > 0; off >>= 1) s += __shfl_xor(s, off, 64);

    const float* ch = chi + (size_t)node * 15;
    float c0 = 0.f, c1 = 0.f, c2 = 0.f;
#pragma unroll
    for (int m = 0; m < 3; ++m)  c0 += ch[m] * ch[m];
#pragma unroll
    for (int m = 3; m < 8; ++m)  c1 += ch[m] * ch[m];
#pragma unroll
    for (int m = 8; m < 15; ++m) c2 += ch[m] * ch[m];

    if (lane < 15) chbo[(size_t)node * 15 + lane] = ch[lane] * s;

    const float cl[3] = {c0, c1, c2};
    bf16_t* arow = A3 + (size_t)node * 1536 + lane * 8;
#pragma unroll
    for (int l = 0; l < 3; ++l) {
        bf16x8 o;
#pragma unroll
        for (int j = 0; j < 8; ++j) o[j] = (bf16_t)(cl[l] * g[j] * g[j]);
        *(bf16x8*)(arow + l * 512) = o;
    }
}

extern "C" void kernel_launch(void* const* d_in, const int* in_sizes, int n_in,
                              void* d_out, int out_size, void* d_ws, size_t ws_size,
                              hipStream_t stream)
{
    const float* x   = (const float*)d_in[0];
    const float* chi = (const float*)d_in[1];
    // d_in[2] = z_one_hot : unused by the reference computation
    const float* W1  = (const float*)d_in[3];
    const float* b1  = (const float*)d_in[4];
    const float* W2  = (const float*)d_in[5];
    const float* W3  = (const float*)d_in[6];
    const float* W4  = (const float*)d_in[7];
    const float* b4  = (const float*)d_in[8];

    char* ws = (char*)d_ws;
    bf16_t* W1b = (bf16_t*)(ws + 0);
    bf16_t* W2t = (bf16_t*)(ws + 524288);
    bf16_t* W4t = (bf16_t*)(ws + 1048576);
    bf16_t* Wct = (bf16_t*)(ws + 2621440);
    float*  bc  = (float*) (ws + 3145728);
    float*  u   = (float*) (ws + 3147776);
    bf16_t* Xb  = (bf16_t*)(ws + 3149824);
    bf16_t* A3  = (bf16_t*)(ws + 3149824);   // overlaps Xb (dead by then)

    float*  xbo  = (float*)d_out;                                // 24576*512 f32
    float*  chbo = (float*)d_out + (size_t)24576 * 512;          // 24576*15 f32
    bf16_t* Gb   = (bf16_t*)d_out;   // bf16 scratch in chunk0 (dead before final GEMM)

    // prep
    cast8_kernel<<<6144, 256, 0, stream>>>(x, Xb, 1572864);
    prep_kernel<<<4224, 256, 0, stream>>>(W1, W1b, W2, W2t, W4, W4t);
    vecmat_kernel<<<2, 256, 0, stream>>>(b1, W1, u);
    vecmat_kernel<<<2, 256, 0, stream>>>(u, W2, bc);

    // Wct = (W1@W2)^T = W2^T @ W1^T
    gemm_bt_kernel<8><<<dim3(2, 2), 512, 0, stream>>>(W2t, W1b, nullptr, Wct, 512, 512, 0);

    // G = x @ (W1@W2) + bc -> bf16
    gemm16_kernel<<<dim3(128, 2), 1024, 0, stream>>>(Xb, Wct, bc, Gb, 512, 512, 0);

    // s, chi_bo, A3
    mid_kernel<<<6144, 256, 0, stream>>>(Gb, chi, W3, chbo, A3);

    // x_bo = silu(A3 @ W4 + b4)
    gemm16_kernel<<<dim3(128, 2), 1024, 0, stream>>>(A3, W4t, b4, xbo, 512, 1536, 1);
}

// Round 12
// 164.267 us; speedup vs baseline: 1.2359x; 1.0564x over previous
//
#include <hip/hip_runtime.h>

typedef __bf16 bf16_t;
typedef __bf16 bf16x8 __attribute__((ext_vector_type(8)));
typedef float f32x4 __attribute__((ext_vector_type(4)));

#define BK 64
#define NNODES 24576

// ws layout (bytes):
//   0        W1b   (512*512 bf16)  = 524288
//   524288   W2t   (512*512 bf16)  = 524288
//   1048576  W4t   (512*1536 bf16) = 1572864
//   2621440  Wct   (512*512 bf16)  = 524288
//   3145728  bc    (512 f32)       = 2048
//   3147776  u     (512 f32)       = 2048
//   3149824  A3    (24576*1536 bf16) = 75497472   [Wctp (4MB f32) overlaps A3
//            head: consumed by wct_reduce BEFORE the G-GEMM writes A3]
// d_out chunk0 (48MB f32 xbo, dead until final GEMM):
//   0        Xb    (24576*512 bf16) = 25165824
//   25165824 c3    (3*24576 f32)    = 294912
//   25460736 s     (24576 f32)      = 98304

__device__ __forceinline__ void g2l16(const void* g, void* l) {
    __builtin_amdgcn_global_load_lds((__attribute__((address_space(1))) void*)(g),
                                     (__attribute__((address_space(3))) void*)(l),
                                     16, 0, 0);
}

#define SB()  __builtin_amdgcn_sched_barrier(0)
#define BAR() __builtin_amdgcn_s_barrier()

// ============ 16-wave GEMM: tile 192x256, BK=64, 1024 threads (R9 core) ====
// mode 0: bf16 store; mode 1: f32 silu store;
// mode 3: G-epilogue — A3[r,l*512+c]=c3[l][r]*g^2 (bf16), s[r] += g.W3 (atomic)
__global__ __launch_bounds__(1024)
void gemm16_kernel(const bf16_t* __restrict__ A, const bf16_t* __restrict__ Bt,
                   const float* __restrict__ bias, void* __restrict__ Cout,
                   int N, int K, int mode,
                   const float* __restrict__ W3, const float* __restrict__ c3v,
                   float* __restrict__ sbuf)
{
    __shared__ __align__(16) bf16_t lA[2][12288];   // 192 rows x 128B per buf
    __shared__ __align__(16) bf16_t lB[2][16384];   // 256 rows x 128B per buf

    const int tid  = threadIdx.x;
    const int lane = tid & 63;
    const int wave = tid >> 6;       // 0..15
    const int wr   = wave >> 2;      // 0..3
    const int wc   = wave & 3;       // 0..3
    const int l15  = lane & 15;
    const int lh   = lane >> 4;      // 0..3

    const int bm = blockIdx.x;
    const int bn = blockIdx.y;

    const size_t strb = (size_t)K * 2;

    const int q0 = tid * 16;
    const size_t ro = (size_t)(q0 >> 7) * strb + ((q0 ^ (((q0 >> 7) & 7) << 4)) & 127);
    const char* gA = (const char*)A  + (size_t)bm * 192 * strb + ro;
    const char* gB = (const char*)Bt + (size_t)bn * 256 * strb + ro;
    char* baseA = (char*)&lA[0][0];
    char* baseB = (char*)&lB[0][0];

    auto stage = [&](int t, int buf) {
        const size_t kb = (size_t)t * 128;
        g2l16(gA + kb, baseA + buf * 24576 + q0);
        if (tid < 512)
            g2l16(gA + kb + 128 * strb, baseA + buf * 24576 + 16384 + q0);
        g2l16(gB + kb, baseB + buf * 32768 + q0);
        g2l16(gB + kb + 128 * strb, baseB + buf * 32768 + 16384 + q0);
    };

    const int swzr = (l15 & 7) << 4;
    const int xk0  = (lh * 16) ^ swzr;
    const int xk1  = (64 + lh * 16) ^ swzr;
    const int aOff = (wr * 48 + l15) * 128;
    const int bOff = (wc * 64 + l15) * 128;

    f32x4 acc[3][4] = {};

    const int T = K / BK;
    stage(0, 0);

    for (int t = 0; t < T; ++t) {
        const int buf = t & 1;

        asm volatile("s_waitcnt vmcnt(0)" ::: "memory");
        BAR();
        SB();

        if (t + 1 < T) stage(t + 1, buf ^ 1);
        SB();

        bf16x8 af[3][2], bf[4][2];
        {
            const char* _pa = baseA + buf * 24576 + aOff;
#pragma unroll
            for (int m = 0; m < 3; ++m) {
                af[m][0] = *(const bf16x8*)(_pa + m * 2048 + xk0);
                af[m][1] = *(const bf16x8*)(_pa + m * 2048 + xk1);
            }
            const char* _pb = baseB + buf * 32768 + bOff;
#pragma unroll
            for (int n = 0; n < 4; ++n) {
                bf[n][0] = *(const bf16x8*)(_pb + n * 2048 + xk0);
                bf[n][1] = *(const bf16x8*)(_pb + n * 2048 + xk1);
            }
        }

        __builtin_amdgcn_s_setprio(1);
#pragma unroll
        for (int m = 0; m < 3; ++m)
#pragma unroll
        for (int n = 0; n < 4; ++n)
#pragma unroll
        for (int kk = 0; kk < 2; ++kk)
            acc[m][n] = __builtin_amdgcn_mfma_f32_16x16x32_bf16(
                af[m][kk], bf[n][kk], acc[m][n], 0, 0, 0);
        __builtin_amdgcn_s_setprio(0);
    }

    // C/D frag layout: col = lane&15, row = (lane>>4)*4 + j
    const int gr0 = bm * 192 + wr * 48 + lh * 4;
    const int gc0 = bn * 256 + wc * 64 + l15;
    if (mode == 0) {
        bf16_t* C = (bf16_t*)Cout;
#pragma unroll
        for (int m = 0; m < 3; ++m)
#pragma unroll
        for (int n = 0; n < 4; ++n) {
            const int c = gc0 + n * 16;
            const float bv = bias ? bias[c] : 0.f;
#pragma unroll
            for (int j = 0; j < 4; ++j)
                C[(size_t)(gr0 + m * 16 + j) * N + c] = (bf16_t)(acc[m][n][j] + bv);
        }
    } else if (mode == 1) {
        float* C = (float*)Cout;
#pragma unroll
        for (int m = 0; m < 3; ++m)
#pragma unroll
        for (int n = 0; n < 4; ++n) {
            const int c = gc0 + n * 16;
            const float bv = bias[c];
#pragma unroll
            for (int j = 0; j < 4; ++j) {
                float v = acc[m][n][j] + bv;
                C[(size_t)(gr0 + m * 16 + j) * N + c] = v / (1.f + __expf(-v));
            }
        }
    } else {
        // mode 3: fused G epilogue
        bf16_t* A3 = (bf16_t*)Cout;
        float w3v[4], bv[4];
#pragma unroll
        for (int n = 0; n < 4; ++n) {
            w3v[n] = W3[gc0 + n * 16];
            bv[n]  = bias[gc0 + n * 16];
        }
#pragma unroll
        for (int m = 0; m < 3; ++m)
#pragma unroll
        for (int j = 0; j < 4; ++j) {
            const int r = gr0 + m * 16 + j;
            float g[4], p = 0.f;
#pragma unroll
            for (int n = 0; n < 4; ++n) {
                g[n] = acc[m][n][j] + bv[n];
                p += g[n] * w3v[n];
            }
            // reduce across the 16 l15-lanes (same row, different cols; lh constant)
            p += __shfl_xor(p, 1); p += __shfl_xor(p, 2);
            p += __shfl_xor(p, 4); p += __shfl_xor(p, 8);
            if (l15 == 0) atomicAdd(&sbuf[r], p);
            const float c0 = c3v[r], c1 = c3v[r + NNODES], c2 = c3v[r + 2 * NNODES];
            bf16_t* arow = A3 + (size_t)r * 1536 + gc0;
#pragma unroll
            for (int n = 0; n < 4; ++n) {
                const float g2 = g[n] * g[n];
                arow[n * 16]        = (bf16_t)(c0 * g2);
                arow[n * 16 + 512]  = (bf16_t)(c1 * g2);
                arow[n * 16 + 1024] = (bf16_t)(c2 * g2);
            }
        }
    }
}

// ============ 8-wave GEMM (split-K) — Wct partials only ============
// LD = row stride (elems) of A and Bt; blockIdx.z selects K-chunk of size K.
__global__ __launch_bounds__(512)
void gemm8_kernel(const bf16_t* __restrict__ A, const bf16_t* __restrict__ Bt,
                  void* __restrict__ Cout, int N, int K, int LD)
{
    __shared__ __align__(16) bf16_t lA[2][16384];   // 256 rows x 128B
    __shared__ __align__(16) bf16_t lB[2][16384];

    const int tid  = threadIdx.x;
    const int lane = tid & 63;
    const int wave = tid >> 6;
    const int wr   = wave >> 2;
    const int wc   = wave & 3;
    const int l15  = lane & 15;
    const int lh   = lane >> 4;

    const int bm = blockIdx.x;
    const int bn = blockIdx.y;
    const int bz = blockIdx.z;

    const size_t strb = (size_t)LD * 2;
    const size_t zoff = (size_t)bz * K * 2;   // byte offset along K

    const int q0 = tid * 16;
    const size_t rowOff = (size_t)(q0 >> 7) * strb + ((q0 ^ (((q0 >> 7) & 7) << 4)) & 127);
    const char* gA = (const char*)A  + (size_t)bm * 256 * strb + zoff + rowOff;
    const char* gB = (const char*)Bt + (size_t)bn * 256 * strb + zoff + rowOff;
    char* baseA = (char*)&lA[0][0];
    char* baseB = (char*)&lB[0][0];

    auto stageA = [&](int t, int buf, int r) {
        g2l16(gA + (size_t)t * 128 + (size_t)(r * 64) * strb,
              baseA + buf * 32768 + r * 8192 + q0);
    };
    auto stageB = [&](int t, int buf, int r) {
        g2l16(gB + (size_t)t * 128 + (size_t)(r * 64) * strb,
              baseB + buf * 32768 + r * 8192 + q0);
    };

    const int swzr = (l15 & 7) << 4;
    const int xk0  = (lh * 16) ^ swzr;
    const int xk1  = (64 + lh * 16) ^ swzr;
    const int aOff = wr * 16384 + l15 * 128;   // 128 rows per wave-row group (FIXED R10 bug)
    const int bOff = wc * 8192 + l15 * 128;

    f32x4 acc[2][2][4][2] = {};

    const int T = K / BK;

#pragma unroll
    for (int r = 0; r < 4; ++r) { stageA(0, 0, r); stageB(0, 0, r); }

    for (int t = 0; t < T; ++t) {
        const int buf = t & 1, nbuf = buf ^ 1;

        asm volatile("s_waitcnt vmcnt(0)" ::: "memory");
        BAR();
        SB();

        if (t + 1 < T) {
#pragma unroll
            for (int r = 0; r < 4; ++r) { stageA(t + 1, nbuf, r); stageB(t + 1, nbuf, r); }
        }
        SB();

        bf16x8 af[8][2], bf[4][2];
        {
            const char* _pa = baseA + buf * 32768 + aOff;
#pragma unroll
            for (int i = 0; i < 8; ++i) {
                af[i][0] = *(const bf16x8*)(_pa + i * 2048 + xk0);
                af[i][1] = *(const bf16x8*)(_pa + i * 2048 + xk1);
            }
            const char* _pb = baseB + buf * 32768 + bOff;
#pragma unroll
            for (int j = 0; j < 4; ++j) {
                bf[j][0] = *(const bf16x8*)(_pb + j * 2048 + xk0);
                bf[j][1] = *(const bf16x8*)(_pb + j * 2048 + xk1);
            }
        }

        __builtin_amdgcn_s_setprio(1);
#pragma unroll
        for (int mh = 0; mh < 2; ++mh)
#pragma unroll
        for (int nh = 0; nh < 2; ++nh)
#pragma unroll
        for (int m = 0; m < 4; ++m)
#pragma unroll
        for (int n = 0; n < 2; ++n)
#pragma unroll
        for (int kk = 0; kk < 2; ++kk)
            acc[mh][nh][m][n] = __builtin_amdgcn_mfma_f32_16x16x32_bf16(
                af[mh * 4 + m][kk], bf[nh * 2 + n][kk], acc[mh][nh][m][n], 0, 0, 0);
        __builtin_amdgcn_s_setprio(0);
    }

    float* C = (float*)Cout + (size_t)bz * 512 * 512;
    const int gr0 = bm * 256 + wr * 128 + lh * 4;
    const int gc0 = bn * 256 + wc * 64 + l15;
#pragma unroll
    for (int mh = 0; mh < 2; ++mh)
#pragma unroll
    for (int nh = 0; nh < 2; ++nh)
#pragma unroll
    for (int m = 0; m < 4; ++m)
#pragma unroll
    for (int n = 0; n < 2; ++n) {
        const int c = gc0 + nh * 32 + n * 16;
#pragma unroll
        for (int j = 0; j < 4; ++j)
            C[(size_t)(gr0 + (mh * 4 + m) * 16 + j) * N + c] = acc[mh][nh][m][n][j];
    }
}

__global__ void wct_reduce_kernel(const float* __restrict__ p, bf16_t* __restrict__ out) {
    const int i = blockIdx.x * 256 + threadIdx.x;   // < 262144
    out[i] = (bf16_t)(p[i] + p[i + 262144] + p[i + 524288] + p[i + 786432]);
}

__global__ void cast8_kernel(const float* __restrict__ in, bf16_t* __restrict__ out, int n8) {
    const int i = blockIdx.x * blockDim.x + threadIdx.x;
    if (i >= n8) return;
    const float4* pp = (const float4*)in + (size_t)i * 2;
    float4 a = pp[0], b = pp[1];
    bf16x8 v;
    v[0] = (bf16_t)a.x; v[1] = (bf16_t)a.y; v[2] = (bf16_t)a.z; v[3] = (bf16_t)a.w;
    v[4] = (bf16_t)b.x; v[5] = (bf16_t)b.y; v[6] = (bf16_t)b.z; v[7] = (bf16_t)b.w;
    *(bf16x8*)(out + (size_t)i * 8) = v;
}

// fused weight prep: [0,128) cast W1; [128,1152) transpose W2; [1152,4224) transpose W4
__global__ void prep_kernel(const float* __restrict__ W1, bf16_t* __restrict__ W1b,
                            const float* __restrict__ W2, bf16_t* __restrict__ W2t,
                            const float* __restrict__ W4, bf16_t* __restrict__ W4t)
{
    const int b = blockIdx.x;
    if (b < 128) {
        const int i = b * 256 + threadIdx.x;
        const float4* p = (const float4*)W1 + (size_t)i * 2;
        float4 a = p[0], c = p[1];
        bf16x8 v;
        v[0] = (bf16_t)a.x; v[1] = (bf16_t)a.y; v[2] = (bf16_t)a.z; v[3] = (bf16_t)a.w;
        v[4] = (bf16_t)c.x; v[5] = (bf16_t)c.y; v[6] = (bf16_t)c.z; v[7] = (bf16_t)c.w;
        *(bf16x8*)(W1b + (size_t)i * 8) = v;
    } else if (b < 1152) {
        const int idx = (b - 128) * 256 + threadIdx.x;
        const int c = idx >> 9, r = idx & 511;
        W2t[idx] = (bf16_t)W2[(size_t)r * 512 + c];
    } else {
        const int idx = (b - 1152) * 256 + threadIdx.x;
        const int c = idx / 1536, r = idx - c * 1536;
        W4t[idx] = (bf16_t)W4[(size_t)r * 512 + c];
    }
}

// u[t] = sum_i v[i] * W[i][t]
__global__ void vecmat_kernel(const float* __restrict__ v, const float* __restrict__ W,
                              float* __restrict__ out) {
    const int t = blockIdx.x * blockDim.x + threadIdx.x;
    if (t >= 512) return;
    float s = 0.f;
    for (int i = 0; i < 512; ++i) s += v[i] * W[i * 512 + t];
    out[t] = s;
}

// c3[l][n] = sum_{m in seg l} chi[n,m]^2  (independent of g)
__global__ void c3_kernel(const float* __restrict__ chi, float* __restrict__ c3) {
    const int n = blockIdx.x * 256 + threadIdx.x;
    if (n >= NNODES) return;
    const float* ch = chi + (size_t)n * 15;
    float a = 0.f, b = 0.f, c = 0.f;
#pragma unroll
    for (int m = 0; m < 3; ++m)  a += ch[m] * ch[m];
#pragma unroll
    for (int m = 3; m < 8; ++m)  b += ch[m] * ch[m];
#pragma unroll
    for (int m = 8; m < 15; ++m) c += ch[m] * ch[m];
    c3[n] = a; c3[n + NNODES] = b; c3[n + 2 * NNODES] = c;
}

// chbo[n,m] = chi[n,m] * s[n]
__global__ void chbo_kernel(const float* __restrict__ chi, const float* __restrict__ s,
                            float* __restrict__ chbo) {
    const int idx = blockIdx.x * 256 + threadIdx.x;
    if (idx >= NNODES * 15) return;
    chbo[idx] = chi[idx] * s[idx / 15];
}

extern "C" void kernel_launch(void* const* d_in, const int* in_sizes, int n_in,
                              void* d_out, int out_size, void* d_ws, size_t ws_size,
                              hipStream_t stream)
{
    const float* x   = (const float*)d_in[0];
    const float* chi = (const float*)d_in[1];
    // d_in[2] = z_one_hot : unused
    const float* W1  = (const float*)d_in[3];
    const float* b1  = (const float*)d_in[4];
    const float* W2  = (const float*)d_in[5];
    const float* W3  = (const float*)d_in[6];
    const float* W4  = (const float*)d_in[7];
    const float* b4  = (const float*)d_in[8];

    char* ws = (char*)d_ws;
    bf16_t* W1b  = (bf16_t*)(ws + 0);
    bf16_t* W2t  = (bf16_t*)(ws + 524288);
    bf16_t* W4t  = (bf16_t*)(ws + 1048576);
    bf16_t* Wct  = (bf16_t*)(ws + 2621440);
    float*  bc   = (float*) (ws + 3145728);
    float*  u    = (float*) (ws + 3147776);
    bf16_t* A3   = (bf16_t*)(ws + 3149824);
    float*  Wctp = (float*) (ws + 3149824);   // overlaps A3 head; dead before A3 written

    float*  xbo  = (float*)d_out;                          // 24576*512 f32
    float*  chbo = (float*)d_out + (size_t)NNODES * 512;   // 24576*15 f32
    // dead region of chunk0 used as scratch until final GEMM:
    char*   c0s  = (char*)d_out;
    bf16_t* Xb   = (bf16_t*)(c0s + 0);            // 25165824
    float*  c3   = (float*) (c0s + 25165824);     // 294912
    float*  sbuf = (float*) (c0s + 25460736);     // 98304

    // prep (independent, serial on stream)
    cast8_kernel<<<6144, 256, 0, stream>>>(x, Xb, 1572864);
    prep_kernel<<<4224, 256, 0, stream>>>(W1, W1b, W2, W2t, W4, W4t);
    vecmat_kernel<<<2, 256, 0, stream>>>(b1, W1, u);
    vecmat_kernel<<<2, 256, 0, stream>>>(u, W2, bc);
    c3_kernel<<<96, 256, 0, stream>>>(chi, c3);
    hipMemsetAsync(sbuf, 0, NNODES * sizeof(float), stream);

    // Wct = (W1@W2)^T via split-K partials + reduce
    gemm8_kernel<<<dim3(2, 2, 4), 512, 0, stream>>>(W2t, W1b, Wctp, 512, 128, 512);
    wct_reduce_kernel<<<1024, 256, 0, stream>>>(Wctp, Wct);

    // G-GEMM fused epilogue: A3 = c_l * g^2 ; s += g.W3
    gemm16_kernel<<<dim3(128, 2), 1024, 0, stream>>>(
        Xb, Wct, bc, A3, 512, 512, 3, W3, c3, sbuf);

    // chi_bo = chi * s
    chbo_kernel<<<1440, 256, 0, stream>>>(chi, sbuf, chbo);

    // x_bo = silu(A3 @ W4 + b4)
    gemm16_kernel<<<dim3(128, 2), 1024, 0, stream>>>(
        A3, W4t, b4, xbo, 512, 1536, 1, nullptr, nullptr, nullptr);
}